// Round 12
// baseline (504.062 us; speedup 1.0000x reference)
//
#include <hip/hip_runtime.h>
#include <hip/hip_bf16.h>

typedef _Float16 f16x2 __attribute__((ext_vector_type(2)));
typedef _Float16 f16x8 __attribute__((ext_vector_type(8)));
typedef float    f32x16 __attribute__((ext_vector_type(16)));

#define IN_DIM   32
#define EDGE_DIM 16
#define HDIM     64
#define OUT_DIM  6
#define BN_EPS   1e-5f

// ============ zero agg slabs + degI (one contiguous region, one dispatch) ============
__global__ void k_zero(uint4* __restrict__ p, int n16) {
    int i = blockIdx.x * 256 + threadIdx.x;
    if (i < n16) p[i] = make_uint4(0u, 0u, 0u, 0u);
}

// ============ fused setup: pack We | transpose be | encode h0 | prep eaH+deg | bounds ============
__global__ __launch_bounds__(256) void k_setup(
    const float* __restrict__ We, uint4* __restrict__ WeB,
    const float* __restrict__ be, float* __restrict__ beT,
    const float* __restrict__ x, const float* __restrict__ Wx,
    const float* __restrict__ bx, float* __restrict__ h,
    const float* __restrict__ ea, _Float16* __restrict__ eaH,
    const int* __restrict__ dstI, int* __restrict__ degI,
    const int* __restrict__ batch, int* __restrict__ start,
    int N, int E, int G, int PACKB, int ENCB, int PREPB)
{
    int bid = blockIdx.x;
    int t = threadIdx.x;
    if (bid < PACKB) {                 // pack: WeB[layer][h*2+oh][lane] f16x8
        int tid = bid * 256 + t;       // lane: col=oh*32+(lane&31), k=8*(lane>>5)+j
        int tile = tid >> 6, lane = tid & 63;
        int layer = tile >> 7;
        int r = tile & 127;
        int hh = r >> 1, oh = r & 1;
        int col = hh * 64 + oh * 32 + (lane & 31);
        int kbase = 8 * (lane >> 5);
        const float* base = We + (size_t)layer * 65536 + col;
        f16x8 v;
        #pragma unroll
        for (int j = 0; j < 8; ++j) v[j] = (_Float16)base[(size_t)(kbase + j) * 4096];
        WeB[(size_t)tile * 64 + lane] = __builtin_bit_cast(uint4, v);
        return;
    }
    bid -= PACKB;
    if (bid < 3) {                     // transpose be -> beT[layer][o][h]
        int layer = bid;
        for (int i = t; i < 4096; i += 256) {
            beT[(size_t)layer * 4096 + (i & 63) * 64 + (i >> 6)] = be[(size_t)layer * 4096 + i];
        }
        return;
    }
    bid -= 3;
    if (bid < ENCB) {                  // encode: h0 = x @ Wx + bx
        int tid = bid * 256 + t;
        int n = tid >> 4, jq = tid & 15;
        if (n >= N) return;
        const float4* W4 = (const float4*)Wx;
        float4 acc = ((const float4*)bx)[jq];
        const float4* xv = (const float4*)(x + (size_t)n * IN_DIM);
        #pragma unroll
        for (int k4 = 0; k4 < 8; ++k4) {
            float4 xk = xv[k4];
            #pragma unroll
            for (int i = 0; i < 4; ++i) {
                float xs = (i == 0) ? xk.x : (i == 1) ? xk.y : (i == 2) ? xk.z : xk.w;
                float4 ww = W4[(k4 * 4 + i) * 16 + jq];
                acc.x += xs * ww.x; acc.y += xs * ww.y; acc.z += xs * ww.z; acc.w += xs * ww.w;
            }
        }
        ((float4*)h)[tid] = acc;
        return;
    }
    bid -= ENCB;
    if (bid < PREPB) {                 // prep: eaH f16 convert + degree count
        int tid = bid * 256 + t;
        int E8 = E * 8;
        if (tid < E8) {
            float2 v = ((const float2*)ea)[tid];
            f16x2 r; r[0] = (_Float16)v.x; r[1] = (_Float16)v.y;
            ((f16x2*)eaH)[tid] = r;
        }
        if (tid < E) atomicAdd(&degI[dstI[tid]], 1);
        return;
    }
    if (t <= G) {                      // bounds (batch sorted)
        int lo = 0, hi = N;
        while (lo < hi) { int mid = (lo + hi) >> 1; if (batch[mid] < t) lo = mid + 1; else hi = mid; }
        start[t] = lo;
    }
}

// ============ fused edge MLP (32x32x16 MFMA, zero-C) + relu*hs reduce + atomic scatter ============
// Block: (64-edge group) x (h-half of 32). 4 waves = (edge-half gp) x (o-half oh).
// PER-HHALF agg SLAB: restores single-concurrent-writer atomics (R11 lesson:
// two blocks atomically hitting the same lines cross-XCD => 30x HBM RMW traffic).
__global__ __launch_bounds__(256, 6) void k_edge(
    const uint4* __restrict__ eaH4, const uint4* __restrict__ WeB,
    const float* __restrict__ beT, const float* __restrict__ hin,
    const int* __restrict__ srcI, const int* __restrict__ dstI,
    float* __restrict__ agg, int E, int N)
{
    __shared__ __align__(16) float hsT[32][68];
    const int t = threadIdx.x;
    const int l = t & 63;
    const int w = t >> 6;
    const int eg = blockIdx.x >> 1;
    const int hhalf = blockIdx.x & 1;
    const int eb = eg * 64;
    const int hbase = hhalf * 32;

    // stage hsT: wave w stages local h-rows w*8..w*8+7 for all 64 edges
    {
        int egc = min(eb + l, E - 1);
        int s = srcI[egc];
        const float4* hp = (const float4*)(hin + (size_t)s * HDIM + hbase + w * 8);
        float4 a = hp[0], b = hp[1];
        hsT[w*8+0][l] = a.x; hsT[w*8+1][l] = a.y; hsT[w*8+2][l] = a.z; hsT[w*8+3][l] = a.w;
        hsT[w*8+4][l] = b.x; hsT[w*8+5][l] = b.y; hsT[w*8+6][l] = b.z; hsT[w*8+7][l] = b.w;
    }
    __syncthreads();

    const int gp = w >> 1, oh = w & 1;
    const int ebw = eb + gp * 32, elw = gp * 32;
    const int row = l & 31, kg = l >> 5, obase = oh * 32;
    int ea_e = min(ebw + row, E - 1);
    f16x8 A = __builtin_bit_cast(f16x8, eaH4[(size_t)ea_e * 2 + kg]);
    float m[16];
    #pragma unroll
    for (int j = 0; j < 16; ++j) m[j] = 0.f;

    const f32x16 zc = (f32x16)0.f;
    const uint4* Bb = WeB + (size_t)oh * 64 + l;
    const float* beTb = beT + (size_t)(obase + row) * 64 + hbase;

    auto step = [&](const uint4& Bv, int hh, float bias) {
        f32x16 z = __builtin_amdgcn_mfma_f32_32x32x16_f16(
            A, __builtin_bit_cast(f16x8, Bv), zc, 0, 0, 0);
        float4 q0 = *(const float4*)&hsT[hh][elw + 4 * kg + 0];
        float4 q1 = *(const float4*)&hsT[hh][elw + 4 * kg + 8];
        float4 q2 = *(const float4*)&hsT[hh][elw + 4 * kg + 16];
        float4 q3 = *(const float4*)&hsT[hh][elw + 4 * kg + 24];
        m[0]  += fmaxf(z[0]  + bias, 0.f) * q0.x;
        m[1]  += fmaxf(z[1]  + bias, 0.f) * q0.y;
        m[2]  += fmaxf(z[2]  + bias, 0.f) * q0.z;
        m[3]  += fmaxf(z[3]  + bias, 0.f) * q0.w;
        m[4]  += fmaxf(z[4]  + bias, 0.f) * q1.x;
        m[5]  += fmaxf(z[5]  + bias, 0.f) * q1.y;
        m[6]  += fmaxf(z[6]  + bias, 0.f) * q1.z;
        m[7]  += fmaxf(z[7]  + bias, 0.f) * q1.w;
        m[8]  += fmaxf(z[8]  + bias, 0.f) * q2.x;
        m[9]  += fmaxf(z[9]  + bias, 0.f) * q2.y;
        m[10] += fmaxf(z[10] + bias, 0.f) * q2.z;
        m[11] += fmaxf(z[11] + bias, 0.f) * q2.w;
        m[12] += fmaxf(z[12] + bias, 0.f) * q3.x;
        m[13] += fmaxf(z[13] + bias, 0.f) * q3.y;
        m[14] += fmaxf(z[14] + bias, 0.f) * q3.z;
        m[15] += fmaxf(z[15] + bias, 0.f) * q3.w;
    };

    uint4 B0 = Bb[(size_t)(hbase + 0) * 128];
    uint4 B1 = Bb[(size_t)(hbase + 1) * 128];
    uint4 B2 = Bb[(size_t)(hbase + 2) * 128];
    uint4 B3 = Bb[(size_t)(hbase + 3) * 128];
    #pragma unroll 1
    for (int hh = 0; hh < 32; hh += 4) {
        uint4 N0 = Bb[(size_t)(hbase + hh + 4) * 128];
        uint4 N1 = Bb[(size_t)(hbase + hh + 5) * 128];
        uint4 N2 = Bb[(size_t)(hbase + hh + 6) * 128];
        uint4 N3 = Bb[(size_t)(hbase + hh + 7) * 128];
        float4 bv = *(const float4*)(beTb + hh);
        step(B0, hh + 0, bv.x);
        step(B1, hh + 1, bv.y);
        step(B2, hh + 2, bv.z);
        step(B3, hh + 3, bv.w);
        B0 = N0; B1 = N1; B2 = N2; B3 = N3;
    }

    // scatter into this h-half's PRIVATE slab (single concurrent writer pattern per address)
    float* aggS = agg + (size_t)hhalf * N * HDIM;
    #pragma unroll
    for (int j = 0; j < 16; ++j) {
        int e = ebw + (j & 3) + 8 * (j >> 2) + 4 * kg;
        if (e < E) atomicAdd(&aggS[(size_t)dstI[e] * HDIM + obase + row], m[j]);
    }
}

// ============ node update: sum slabs, mean, root GEMV, relu, BN(eval), residual; self-zeroes ============
__global__ void k_update(
    float* __restrict__ agg, const int* __restrict__ degI,
    const float* __restrict__ hin, const float* __restrict__ Wroot,
    const float* __restrict__ broot, const float* __restrict__ gam,
    const float* __restrict__ bet, const float* __restrict__ rmean,
    const float* __restrict__ rvar, float* __restrict__ hout, int N)
{
    int tid = blockIdx.x * 256 + threadIdx.x;
    int n = tid >> 4, jq = tid & 15;
    if (n >= N) return;
    float dinv = 1.0f / fmaxf((float)degI[n], 1.0f);
    float4 acc = ((const float4*)broot)[jq];
    float4 a0 = ((const float4*)agg)[tid];
    float4 a1 = ((const float4*)agg)[(size_t)N * 16 + tid];
    ((float4*)agg)[tid] = make_float4(0.f, 0.f, 0.f, 0.f);
    ((float4*)agg)[(size_t)N * 16 + tid] = make_float4(0.f, 0.f, 0.f, 0.f);
    acc.x += (a0.x + a1.x) * dinv; acc.y += (a0.y + a1.y) * dinv;
    acc.z += (a0.z + a1.z) * dinv; acc.w += (a0.w + a1.w) * dinv;
    const float4* W4 = (const float4*)Wroot;
    const float4* hv = (const float4*)(hin + (size_t)n * HDIM);
    #pragma unroll
    for (int k4 = 0; k4 < 16; ++k4) {
        float4 hk = hv[k4];
        #pragma unroll
        for (int i = 0; i < 4; ++i) {
            float hsc = (i == 0) ? hk.x : (i == 1) ? hk.y : (i == 2) ? hk.z : hk.w;
            float4 ww = W4[(k4 * 4 + i) * 16 + jq];
            acc.x += hsc * ww.x; acc.y += hsc * ww.y; acc.z += hsc * ww.z; acc.w += hsc * ww.w;
        }
    }
    acc.x = fmaxf(acc.x, 0.f); acc.y = fmaxf(acc.y, 0.f);
    acc.z = fmaxf(acc.z, 0.f); acc.w = fmaxf(acc.w, 0.f);
    float4 g4 = ((const float4*)gam)[jq];
    float4 b4 = ((const float4*)bet)[jq];
    float4 mm4 = ((const float4*)rmean)[jq];
    float4 v4 = ((const float4*)rvar)[jq];
    float4 hres = ((const float4*)hin)[tid];
    float4 y;
    y.x = g4.x * (acc.x - mm4.x) * rsqrtf(v4.x + BN_EPS) + b4.x + hres.x;
    y.y = g4.y * (acc.y - mm4.y) * rsqrtf(v4.y + BN_EPS) + b4.y + hres.y;
    y.z = g4.z * (acc.z - mm4.z) * rsqrtf(v4.z + BN_EPS) + b4.z + hres.z;
    y.w = g4.w * (acc.w - mm4.w) * rsqrtf(v4.w + BN_EPS) + b4.w + hres.w;
    ((float4*)hout)[tid] = y;
}

// ============ fused pool (segment mean) + MLP head; no atomics ============
__global__ __launch_bounds__(256) void k_pool_head(
    const float* __restrict__ h, const int* __restrict__ start,
    const float* __restrict__ W1, const float* __restrict__ b1,
    const float* __restrict__ W2, const float* __restrict__ b2,
    float* __restrict__ out)
{
    __shared__ float sums[16][68];
    __shared__ float pl[HDIM];
    __shared__ float zl[HDIM];
    int g = blockIdx.x;
    int s0 = start[g], s1 = start[g + 1];
    int t = threadIdx.x, jq = t & 15, rp = t >> 4;
    float4 acc = make_float4(0.f, 0.f, 0.f, 0.f);
    for (int n = s0 + rp; n < s1; n += 16) {
        float4 v = ((const float4*)h)[(size_t)n * 16 + jq];
        acc.x += v.x; acc.y += v.y; acc.z += v.z; acc.w += v.w;
    }
    *(float4*)&sums[rp][jq * 4] = acc;
    __syncthreads();
    if (t < HDIM) {
        float a = 0.f;
        #pragma unroll
        for (int r = 0; r < 16; ++r) a += sums[r][t];
        pl[t] = a / fmaxf((float)(s1 - s0), 1.0f);
    }
    __syncthreads();
    if (t < HDIM) {
        float a = b1[t];
        #pragma unroll
        for (int k = 0; k < HDIM; ++k) a += pl[k] * W1[k * HDIM + t];
        zl[t] = fmaxf(a, 0.f);
    }
    __syncthreads();
    if (t < OUT_DIM) {
        float a = b2[t];
        #pragma unroll
        for (int k = 0; k < HDIM; ++k) a += zl[k] * W2[k * OUT_DIM + t];
        out[(size_t)g * OUT_DIM + t] = a;
    }
}

// ============ launch: 9 dispatches, no cooperative sync ============
extern "C" void kernel_launch(void* const* d_in, const int* in_sizes, int n_in,
                              void* d_out, int out_size, void* d_ws, size_t ws_size,
                              hipStream_t stream) {
    const float* x     = (const float*)d_in[0];
    const float* eattr = (const float*)d_in[1];
    const int*   src   = (const int*)d_in[2];
    const int*   dst   = (const int*)d_in[3];
    const int*   batch = (const int*)d_in[4];
    const float* Wx    = (const float*)d_in[5];
    const float* bx    = (const float*)d_in[6];
    const float* We    = (const float*)d_in[7];
    const float* be    = (const float*)d_in[8];
    const float* Wroot = (const float*)d_in[9];
    const float* broot = (const float*)d_in[10];
    const float* gam   = (const float*)d_in[11];
    const float* bet   = (const float*)d_in[12];
    const float* rmean = (const float*)d_in[13];
    const float* rvar  = (const float*)d_in[14];
    const float* W1    = (const float*)d_in[15];
    const float* b1    = (const float*)d_in[16];
    const float* W2    = (const float*)d_in[17];
    const float* b2    = (const float*)d_in[18];
    float* out = (float*)d_out;

    const int N = in_sizes[0] / IN_DIM;
    const int E = in_sizes[2];
    const int G = out_size / OUT_DIM;

    char* ws = (char*)d_ws;
    size_t off = 0;
    auto alloc = [&](size_t bytes) -> void* {
        void* p = ws + off;
        off = (off + bytes + 255) & ~(size_t)255;
        return p;
    };
    float*    h0    = (float*)alloc((size_t)N * HDIM * 4);
    float*    h1    = (float*)alloc((size_t)N * HDIM * 4);
    _Float16* eaH   = (_Float16*)alloc((size_t)E * 16 * 2);
    uint4*    WeB   = (uint4*)alloc((size_t)3 * 128 * 64 * 16 + 65536);  // +64KB tail pad
    float*    beT   = (float*)alloc((size_t)3 * 4096 * 4);
    int*      start = (int*)alloc((size_t)(G + 1) * 4);
    // contiguous zero region: agg (2 slabs) + degI
    size_t zoff = off;
    float*    agg   = (float*)alloc((size_t)2 * N * HDIM * 4);
    int*      degI  = (int*)alloc((size_t)N * 4);
    size_t zbytes = off - zoff;
    (void)ws_size; (void)n_in;

    const int n16 = (int)(zbytes / 16);
    k_zero<<<(n16 + 255) / 256, 256, 0, stream>>>((uint4*)agg, n16);

    const int PACKB = 96;
    const int ENCB  = (N * 16 + 255) / 256;
    const int PREPB = (E * 8 + 255) / 256;
    k_setup<<<PACKB + 3 + ENCB + PREPB + 1, 256, 0, stream>>>(
        We, WeB, be, beT, x, Wx, bx, h0, eattr, eaH, dst, degI, batch, start,
        N, E, G, PACKB, ENCB, PREPB);

    const float* hin = h0;
    float* hout = h1;
    const int edgeBlocks = ((E + 63) / 64) * 2;
    for (int l = 0; l < 3; ++l) {
        k_edge<<<edgeBlocks, 256, 0, stream>>>(
            (const uint4*)eaH, WeB + (size_t)l * 8192, beT + (size_t)l * 4096,
            hin, src, dst, agg, E, N);
        k_update<<<(N * 16 + 255) / 256, 256, 0, stream>>>(
            agg, degI, hin, Wroot + (size_t)l * 4096, broot + (size_t)l * 64,
            gam + (size_t)l * 64, bet + (size_t)l * 64, rmean + (size_t)l * 64,
            rvar + (size_t)l * 64, hout, N);
        float* tmp = hout; hout = (float*)hin; hin = tmp;
    }
    k_pool_head<<<G, 256, 0, stream>>>(hin, start, W1, b1, W2, b2, out);
}

// Round 13
// 224.565 us; speedup vs baseline: 2.2446x; 2.2446x over previous
//
#include <hip/hip_runtime.h>
#include <hip/hip_bf16.h>

typedef _Float16 f16x2 __attribute__((ext_vector_type(2)));
typedef _Float16 f16x8 __attribute__((ext_vector_type(8)));
typedef float    f32x16 __attribute__((ext_vector_type(16)));

#define IN_DIM   32
#define EDGE_DIM 16
#define HDIM     64
#define OUT_DIM  6
#define BN_EPS   1e-5f

typedef __attribute__((address_space(1))) const void GASV;
typedef __attribute__((address_space(3))) void LASV;

// ============ zero agg+degI (one contiguous region, one dispatch) ============
__global__ void k_zero(uint4* __restrict__ p, int n16) {
    int i = blockIdx.x * 256 + threadIdx.x;
    if (i < n16) p[i] = make_uint4(0u, 0u, 0u, 0u);
}

// ============ fused setup: pack We (32x32 B-frags) | encode h0 | prep eaH+deg | bounds ============
__global__ __launch_bounds__(256) void k_setup(
    const float* __restrict__ We, uint4* __restrict__ WeB,
    const float* __restrict__ x, const float* __restrict__ Wx,
    const float* __restrict__ bx, float* __restrict__ h,
    const float* __restrict__ ea, _Float16* __restrict__ eaH,
    const int* __restrict__ dstI, int* __restrict__ degI,
    const int* __restrict__ batch, int* __restrict__ start,
    int N, int E, int G, int PACKB, int ENCB, int PREPB)
{
    int bid = blockIdx.x;
    int t = threadIdx.x;
    if (bid < PACKB) {                 // pack: WeB[layer][h*2+oh][lane] f16x8
        int tid = bid * 256 + t;       // lane: col=oh*32+(lane&31), k=8*(lane>>5)+j
        int tile = tid >> 6, lane = tid & 63;
        int layer = tile >> 7;
        int r = tile & 127;
        int hh = r >> 1, oh = r & 1;
        int col = hh * 64 + oh * 32 + (lane & 31);
        int kbase = 8 * (lane >> 5);
        const float* base = We + (size_t)layer * 65536 + col;
        f16x8 v;
        #pragma unroll
        for (int j = 0; j < 8; ++j) v[j] = (_Float16)base[(size_t)(kbase + j) * 4096];
        WeB[(size_t)tile * 64 + lane] = __builtin_bit_cast(uint4, v);
        return;
    }
    bid -= PACKB;
    if (bid < ENCB) {                  // encode: h0 = x @ Wx + bx
        int tid = bid * 256 + t;
        int n = tid >> 4, jq = tid & 15;
        if (n >= N) return;
        const float4* W4 = (const float4*)Wx;
        float4 acc = ((const float4*)bx)[jq];
        const float4* xv = (const float4*)(x + (size_t)n * IN_DIM);
        #pragma unroll
        for (int k4 = 0; k4 < 8; ++k4) {
            float4 xk = xv[k4];
            #pragma unroll
            for (int i = 0; i < 4; ++i) {
                float xs = (i == 0) ? xk.x : (i == 1) ? xk.y : (i == 2) ? xk.z : xk.w;
                float4 ww = W4[(k4 * 4 + i) * 16 + jq];
                acc.x += xs * ww.x; acc.y += xs * ww.y; acc.z += xs * ww.z; acc.w += xs * ww.w;
            }
        }
        ((float4*)h)[tid] = acc;
        return;
    }
    bid -= ENCB;
    if (bid < PREPB) {                 // prep: eaH f16 convert + degree count
        int tid = bid * 256 + t;
        int E8 = E * 8;
        if (tid < E8) {
            float2 v = ((const float2*)ea)[tid];
            f16x2 r; r[0] = (_Float16)v.x; r[1] = (_Float16)v.y;
            ((f16x2*)eaH)[tid] = r;
        }
        if (tid < E) atomicAdd(&degI[dstI[tid]], 1);
        return;
    }
    if (t <= G) {                      // bounds (batch sorted)
        int lo = 0, hi = N;
        while (lo < hi) { int mid = (lo + hi) >> 1; if (batch[mid] < t) lo = mid + 1; else hi = mid; }
        start[t] = lo;
    }
}

// ============ fused edge MLP (32x32x16 MFMA) + relu*hs reduce + atomic scatter ============
// R10 structure (64-edge blocks, full 64 h, single-writer atomics) + wave-private
// global_load_lds B-ring: 4 slots x 1KB/wave, 3 in flight, counted vmcnt(2).
// No VGPR results -> compiler cannot fold the pipeline (R10 lesson: VGPR=52 proved folding).
__global__ __launch_bounds__(256, 3) void k_edge(
    const uint4* __restrict__ eaH4, const uint4* __restrict__ WeB,
    const float* __restrict__ be, const float* __restrict__ hin,
    const int* __restrict__ srcI, const int* __restrict__ dstI,
    float* __restrict__ agg, int E)
{
    __shared__ __align__(16) float hsT[64][68];      // 17408 B
    __shared__ float beL[4096];                      // 16384 B
    __shared__ __align__(16) uint4 Bring[4][4][64];  // 16384 B: [wave][slot][lane]
    const int t = threadIdx.x;
    const int l = t & 63;
    const int w = t >> 6;
    const int eb = blockIdx.x * 64;

    // ---- stage beL (this layer's 4096 biases) ----
    {
        const float4* bg = (const float4*)be;
        float4* bs = (float4*)beL;
        for (int i = t; i < 1024; i += 256) bs[i] = bg[i];
    }
    // ---- stage hsT: wave w stages h-rows w*16..w*16+15 for all 64 edges ----
    {
        int egc = min(eb + l, E - 1);
        int s = srcI[egc];
        const float4* hp = (const float4*)(hin + (size_t)s * HDIM + w * 16);
        float4 a = hp[0], b = hp[1], c = hp[2], d = hp[3];
        hsT[w*16+ 0][l] = a.x; hsT[w*16+ 1][l] = a.y; hsT[w*16+ 2][l] = a.z; hsT[w*16+ 3][l] = a.w;
        hsT[w*16+ 4][l] = b.x; hsT[w*16+ 5][l] = b.y; hsT[w*16+ 6][l] = b.z; hsT[w*16+ 7][l] = b.w;
        hsT[w*16+ 8][l] = c.x; hsT[w*16+ 9][l] = c.y; hsT[w*16+10][l] = c.z; hsT[w*16+11][l] = c.w;
        hsT[w*16+12][l] = d.x; hsT[w*16+13][l] = d.y; hsT[w*16+14][l] = d.z; hsT[w*16+15][l] = d.w;
    }
    const int gp = w >> 1, oh = w & 1;
    const int ebw = eb + gp * 32, elw = gp * 32;
    const int row = l & 31, kg = l >> 5, obase = oh * 32;

    // ---- ring prologue: issue slots 0..2 (3 in flight) BEFORE barrier (overlap drain) ----
    const uint4* gsrc = WeB + (size_t)oh * 64 + l;   // + h*128 per h
    #pragma unroll
    for (int s = 0; s < 3; ++s) {
        __builtin_amdgcn_global_load_lds((GASV*)(gsrc + (size_t)s * 128),
                                         (LASV*)&Bring[w][s][0], 16, 0, 0);
    }
    __syncthreads();

    int ea_e = min(ebw + row, E - 1);
    f16x8 A = __builtin_bit_cast(f16x8, eaH4[(size_t)ea_e * 2 + kg]);
    float m[16];
    #pragma unroll
    for (int j = 0; j < 16; ++j) m[j] = 0.f;
    const f32x16 zc = (f32x16)0.f;

    #pragma unroll 1
    for (int hh = 0; hh < 64; ++hh) {
        asm volatile("s_waitcnt vmcnt(2)" ::: "memory");   // slot hh's load complete
        __builtin_amdgcn_sched_barrier(0);
        uint4 Bv = Bring[w][hh & 3][l];                    // ds_read_b128
        float bias = beL[hh * 64 + obase + row];
        f32x16 z = __builtin_amdgcn_mfma_f32_32x32x16_f16(
            A, __builtin_bit_cast(f16x8, Bv), zc, 0, 0, 0);
        // refill the slot consumed at iter hh-1 (lgkm-complete long ago; WAR-safe)
        int hn = (hh + 3) & 63;                            // clamp keeps vmcnt invariant + in-bounds
        __builtin_amdgcn_global_load_lds((GASV*)(gsrc + (size_t)hn * 128),
                                         (LASV*)&Bring[w][hn & 3][0], 16, 0, 0);
        float4 q0 = *(const float4*)&hsT[hh][elw + 4 * kg + 0];
        float4 q1 = *(const float4*)&hsT[hh][elw + 4 * kg + 8];
        float4 q2 = *(const float4*)&hsT[hh][elw + 4 * kg + 16];
        float4 q3 = *(const float4*)&hsT[hh][elw + 4 * kg + 24];
        m[0]  += fmaxf(z[0]  + bias, 0.f) * q0.x;
        m[1]  += fmaxf(z[1]  + bias, 0.f) * q0.y;
        m[2]  += fmaxf(z[2]  + bias, 0.f) * q0.z;
        m[3]  += fmaxf(z[3]  + bias, 0.f) * q0.w;
        m[4]  += fmaxf(z[4]  + bias, 0.f) * q1.x;
        m[5]  += fmaxf(z[5]  + bias, 0.f) * q1.y;
        m[6]  += fmaxf(z[6]  + bias, 0.f) * q1.z;
        m[7]  += fmaxf(z[7]  + bias, 0.f) * q1.w;
        m[8]  += fmaxf(z[8]  + bias, 0.f) * q2.x;
        m[9]  += fmaxf(z[9]  + bias, 0.f) * q2.y;
        m[10] += fmaxf(z[10] + bias, 0.f) * q2.z;
        m[11] += fmaxf(z[11] + bias, 0.f) * q2.w;
        m[12] += fmaxf(z[12] + bias, 0.f) * q3.x;
        m[13] += fmaxf(z[13] + bias, 0.f) * q3.y;
        m[14] += fmaxf(z[14] + bias, 0.f) * q3.z;
        m[15] += fmaxf(z[15] + bias, 0.f) * q3.w;
    }

    // ---- scatter: one f32 atomic per (e,o); single-writer, wave-coalesced (R10 pattern) ----
    #pragma unroll
    for (int j = 0; j < 16; ++j) {
        int e = ebw + (j & 3) + 8 * (j >> 2) + 4 * kg;
        if (e < E) atomicAdd(&agg[(size_t)dstI[e] * HDIM + obase + row], m[j]);
    }
}

// ============ node update: mean, root GEMV, relu, BN(eval), residual; self-zeroes agg ============
__global__ void k_update(
    float* __restrict__ agg, const int* __restrict__ degI,
    const float* __restrict__ hin, const float* __restrict__ Wroot,
    const float* __restrict__ broot, const float* __restrict__ gam,
    const float* __restrict__ bet, const float* __restrict__ rmean,
    const float* __restrict__ rvar, float* __restrict__ hout, int N)
{
    int tid = blockIdx.x * 256 + threadIdx.x;
    int n = tid >> 4, jq = tid & 15;
    if (n >= N) return;
    float dinv = 1.0f / fmaxf((float)degI[n], 1.0f);
    float4 acc = ((const float4*)broot)[jq];
    float4 ag = ((const float4*)agg)[tid];
    ((float4*)agg)[tid] = make_float4(0.f, 0.f, 0.f, 0.f);
    acc.x += ag.x * dinv; acc.y += ag.y * dinv; acc.z += ag.z * dinv; acc.w += ag.w * dinv;
    const float4* W4 = (const float4*)Wroot;
    const float4* hv = (const float4*)(hin + (size_t)n * HDIM);
    #pragma unroll
    for (int k4 = 0; k4 < 16; ++k4) {
        float4 hk = hv[k4];
        #pragma unroll
        for (int i = 0; i < 4; ++i) {
            float hsc = (i == 0) ? hk.x : (i == 1) ? hk.y : (i == 2) ? hk.z : hk.w;
            float4 ww = W4[(k4 * 4 + i) * 16 + jq];
            acc.x += hsc * ww.x; acc.y += hsc * ww.y; acc.z += hsc * ww.z; acc.w += hsc * ww.w;
        }
    }
    acc.x = fmaxf(acc.x, 0.f); acc.y = fmaxf(acc.y, 0.f);
    acc.z = fmaxf(acc.z, 0.f); acc.w = fmaxf(acc.w, 0.f);
    float4 g4 = ((const float4*)gam)[jq];
    float4 b4 = ((const float4*)bet)[jq];
    float4 mm4 = ((const float4*)rmean)[jq];
    float4 v4 = ((const float4*)rvar)[jq];
    float4 hres = ((const float4*)hin)[tid];
    float4 y;
    y.x = g4.x * (acc.x - mm4.x) * rsqrtf(v4.x + BN_EPS) + b4.x + hres.x;
    y.y = g4.y * (acc.y - mm4.y) * rsqrtf(v4.y + BN_EPS) + b4.y + hres.y;
    y.z = g4.z * (acc.z - mm4.z) * rsqrtf(v4.z + BN_EPS) + b4.z + hres.z;
    y.w = g4.w * (acc.w - mm4.w) * rsqrtf(v4.w + BN_EPS) + b4.w + hres.w;
    ((float4*)hout)[tid] = y;
}

// ============ fused pool (segment mean) + MLP head; no atomics ============
__global__ __launch_bounds__(256) void k_pool_head(
    const float* __restrict__ h, const int* __restrict__ start,
    const float* __restrict__ W1, const float* __restrict__ b1,
    const float* __restrict__ W2, const float* __restrict__ b2,
    float* __restrict__ out)
{
    __shared__ float sums[16][68];
    __shared__ float pl[HDIM];
    __shared__ float zl[HDIM];
    int g = blockIdx.x;
    int s0 = start[g], s1 = start[g + 1];
    int t = threadIdx.x, jq = t & 15, rp = t >> 4;
    float4 acc = make_float4(0.f, 0.f, 0.f, 0.f);
    for (int n = s0 + rp; n < s1; n += 16) {
        float4 v = ((const float4*)h)[(size_t)n * 16 + jq];
        acc.x += v.x; acc.y += v.y; acc.z += v.z; acc.w += v.w;
    }
    *(float4*)&sums[rp][jq * 4] = acc;
    __syncthreads();
    if (t < HDIM) {
        float a = 0.f;
        #pragma unroll
        for (int r = 0; r < 16; ++r) a += sums[r][t];
        pl[t] = a / fmaxf((float)(s1 - s0), 1.0f);
    }
    __syncthreads();
    if (t < HDIM) {
        float a = b1[t];
        #pragma unroll
        for (int k = 0; k < HDIM; ++k) a += pl[k] * W1[k * HDIM + t];
        zl[t] = fmaxf(a, 0.f);
    }
    __syncthreads();
    if (t < OUT_DIM) {
        float a = b2[t];
        #pragma unroll
        for (int k = 0; k < HDIM; ++k) a += zl[k] * W2[k * OUT_DIM + t];
        out[(size_t)g * OUT_DIM + t] = a;
    }
}

// ============ launch: 9 dispatches, no cooperative sync ============
extern "C" void kernel_launch(void* const* d_in, const int* in_sizes, int n_in,
                              void* d_out, int out_size, void* d_ws, size_t ws_size,
                              hipStream_t stream) {
    const float* x     = (const float*)d_in[0];
    const float* eattr = (const float*)d_in[1];
    const int*   src   = (const int*)d_in[2];
    const int*   dst   = (const int*)d_in[3];
    const int*   batch = (const int*)d_in[4];
    const float* Wx    = (const float*)d_in[5];
    const float* bx    = (const float*)d_in[6];
    const float* We    = (const float*)d_in[7];
    const float* be    = (const float*)d_in[8];
    const float* Wroot = (const float*)d_in[9];
    const float* broot = (const float*)d_in[10];
    const float* gam   = (const float*)d_in[11];
    const float* bet   = (const float*)d_in[12];
    const float* rmean = (const float*)d_in[13];
    const float* rvar  = (const float*)d_in[14];
    const float* W1    = (const float*)d_in[15];
    const float* b1    = (const float*)d_in[16];
    const float* W2    = (const float*)d_in[17];
    const float* b2    = (const float*)d_in[18];
    float* out = (float*)d_out;

    const int N = in_sizes[0] / IN_DIM;
    const int E = in_sizes[2];
    const int G = out_size / OUT_DIM;

    char* ws = (char*)d_ws;
    size_t off = 0;
    auto alloc = [&](size_t bytes) -> void* {
        void* p = ws + off;
        off = (off + bytes + 255) & ~(size_t)255;
        return p;
    };
    float*    h0    = (float*)alloc((size_t)N * HDIM * 4);
    float*    h1    = (float*)alloc((size_t)N * HDIM * 4);
    _Float16* eaH   = (_Float16*)alloc((size_t)E * 16 * 2);
    uint4*    WeB   = (uint4*)alloc((size_t)3 * 128 * 64 * 16);
    int*      start = (int*)alloc((size_t)(G + 1) * 4);
    // contiguous zero region: agg + degI
    size_t zoff = off;
    float*    agg   = (float*)alloc((size_t)N * HDIM * 4);
    int*      degI  = (int*)alloc((size_t)N * 4);
    size_t zbytes = off - zoff;
    (void)ws_size; (void)n_in;

    const int n16 = (int)(zbytes / 16);
    k_zero<<<(n16 + 255) / 256, 256, 0, stream>>>((uint4*)agg, n16);

    const int PACKB = 96;
    const int ENCB  = (N * 16 + 255) / 256;
    const int PREPB = (E * 8 + 255) / 256;
    k_setup<<<PACKB + ENCB + PREPB + 1, 256, 0, stream>>>(
        We, WeB, x, Wx, bx, h0, eattr, eaH, dst, degI, batch, start,
        N, E, G, PACKB, ENCB, PREPB);

    const float* hin = h0;
    float* hout = h1;
    const int edgeBlocks = (E + 63) / 64;
    for (int l = 0; l < 3; ++l) {
        k_edge<<<edgeBlocks, 256, 0, stream>>>(
            (const uint4*)eaH, WeB + (size_t)l * 8192, be + (size_t)l * 4096,
            hin, src, dst, agg, E);
        k_update<<<(N * 16 + 255) / 256, 256, 0, stream>>>(
            agg, degI, hin, Wroot + (size_t)l * 4096, broot + (size_t)l * 64,
            gam + (size_t)l * 64, bet + (size_t)l * 64, rmean + (size_t)l * 64,
            rvar + (size_t)l * 64, hout, N);
        float* tmp = hout; hout = (float*)hin; hin = tmp;
    }
    k_pool_head<<<G, 256, 0, stream>>>(hin, start, W1, b1, W2, b2, out);
}